// Round 8
// baseline (230.960 us; speedup 1.0000x reference)
//
#include <hip/hip_runtime.h>
#include <stdint.h>

typedef unsigned short u16;
typedef __bf16 bf16x8 __attribute__((ext_vector_type(8)));
typedef float f32x4 __attribute__((ext_vector_type(4)));

static constexpr int kDim   = 1024;
static constexpr int kHeads = 16;
static constexpr int kN     = 2048;   // sequence length (power of two!)
static constexpr int kB     = 2;
static constexpr int kTok   = 4096;   // kB * kN

// ---------------- workspace byte offsets ----------------
static constexpr size_t OFF_XB   = 0;                                   // x in bf16      [4096][1024]
static constexpr size_t OFF_VT   = OFF_XB   + (size_t)kTok*kDim*2;      // v^T bf16       [b*1024+c][2048]
static constexpr size_t OFF_OC   = OFF_VT   + (size_t)kTok*kDim*2;      // conv out bf16  [4096][1024]
static constexpr size_t OFF_WVB  = OFF_OC   + (size_t)kTok*kDim*2;      // wv bf16
static constexpr size_t OFF_WPB  = OFF_WVB  + (size_t)kDim*kDim*2;      // wp bf16 (contiguous after wvb!)
static constexpr size_t OFF_PART = OFF_WPB  + (size_t)kDim*kDim*2;      // [2][16][1024] f32 partial col-sums
static constexpr size_t OFF_WZ   = OFF_PART + (size_t)kB*16*kDim*4;     // [32][1024] f32
static constexpr size_t OFF_Z    = OFF_WZ   + (size_t)kB*kHeads*kDim*4; // [32][2048] f32

// ---------------- helpers ----------------
__device__ __forceinline__ u16 f2bf(float f) {
  unsigned int u = __builtin_bit_cast(unsigned int, f);
  u = (u + 0x7FFFu + ((u >> 16) & 1u)) >> 16;   // RNE
  return (u16)u;
}

// async global->LDS, 16B per lane; LDS dest is wave-uniform base + lane*16
__device__ __forceinline__ void gload_lds16(const void* g, void* l) {
  __builtin_amdgcn_global_load_lds(
      (const __attribute__((address_space(1))) unsigned int*)g,
      (__attribute__((address_space(3))) unsigned int*)l, 16, 0, 0);
}

// ---------------- K1: all conversions + x column partial sums ----------------
// blocks [0,2048): wv|wp f32 -> bf16 (contiguous out). blocks [2048,2176): x -> xb + part.
__global__ void cvt_all_kernel(const float* __restrict__ x, const float* __restrict__ wv,
                               const float* __restrict__ wp, u16* __restrict__ xb,
                               u16* __restrict__ wvb, float* __restrict__ part) {
  int bid = blockIdx.x;
  if (bid < 2048) {
    int i = bid * 256 + threadIdx.x;             // [0, 524288) float4s
    const int half = kDim * kDim / 4;            // 262144
    float4 f = (i < half) ? reinterpret_cast<const float4*>(wv)[i]
                          : reinterpret_cast<const float4*>(wp)[i - half];
    unsigned int lo = (unsigned int)f2bf(f.x) | ((unsigned int)f2bf(f.y) << 16);
    unsigned int hi = (unsigned int)f2bf(f.z) | ((unsigned int)f2bf(f.w) << 16);
    reinterpret_cast<uint2*>(wvb)[i] = make_uint2(lo, hi);
    return;
  }
  int b2 = bid - 2048;                           // 128 blocks: b(2) x nchunk(16) x cchunk(4)
  int cc = b2 & 3, nc = (b2 >> 2) & 15, b = b2 >> 6;
  int tid = threadIdx.x, rg = tid >> 6, cl = tid & 63;
  int col = cc * 256 + cl * 4;
  size_t base = (size_t)b * kN + nc * 128;
  float4 s = make_float4(0.f, 0.f, 0.f, 0.f);
  for (int n = rg; n < 128; n += 4) {
    size_t idx = (base + n) * kDim + col;
    float4 v = *reinterpret_cast<const float4*>(&x[idx]);
    unsigned int lo = (unsigned int)f2bf(v.x) | ((unsigned int)f2bf(v.y) << 16);
    unsigned int hi = (unsigned int)f2bf(v.z) | ((unsigned int)f2bf(v.w) << 16);
    *reinterpret_cast<uint2*>(&xb[idx]) = make_uint2(lo, hi);
    s.x += v.x; s.y += v.y; s.z += v.z; s.w += v.w;
  }
  __shared__ float ps[4][256];
  ps[rg][cl * 4 + 0] = s.x; ps[rg][cl * 4 + 1] = s.y;
  ps[rg][cl * 4 + 2] = s.z; ps[rg][cl * 4 + 3] = s.w;
  __syncthreads();
  float tot = ps[0][tid] + ps[1][tid] + ps[2][tid] + ps[3][tid];
  part[((size_t)(b * 16 + nc)) * kDim + cc * 256 + tid] = tot;
}

// ---------------- K2: fused xsum-reduce + kavg + wz ----------------
// 128 blocks = bh(32) x colchunk(4), 256 thr. Per block: xsum in LDS (redundant x4),
// all 64 kavg[d] for this (b,h) (4 thr per d), then 256 wz columns.
__global__ void kwz_kernel(const float* __restrict__ part, const float* __restrict__ wk,
                           const float* __restrict__ wq, float* __restrict__ wz) {
  int blk = blockIdx.x;
  int cc = blk & 3, bh = blk >> 2;
  int b = bh >> 4, h = bh & 15, tid = threadIdx.x;
  __shared__ float xsl[1024];
  __shared__ float kl[64];
  {
    f32x4 s = (f32x4){0.f, 0.f, 0.f, 0.f};
#pragma unroll
    for (int ch = 0; ch < 16; ++ch)
      s += *reinterpret_cast<const f32x4*>(&part[((size_t)(b * 16 + ch)) * kDim + tid * 4]);
    *reinterpret_cast<f32x4*>(&xsl[tid * 4]) = s;
  }
  __syncthreads();
  int d = tid >> 2, pt = tid & 3;
  const float* wkr = wk + (size_t)(h * 64 + d) * kDim;
  float s = 0.f;
  for (int k = pt; k < kDim; k += 4) s += xsl[k] * wkr[k];
  s += __shfl_xor(s, 1);
  s += __shfl_xor(s, 2);
  if (pt == 0) kl[d] = s * (1.0f / (float)kN);
  __syncthreads();
  int col = cc * 256 + tid;
  float a = 0.f;
  const float* wqc = wq + (size_t)h * 64 * kDim + col;
#pragma unroll
  for (int dd = 0; dd < 64; ++dd) a += kl[dd] * wqc[(size_t)dd * kDim];
  wz[(size_t)bh * kDim + col] = a * 0.125f;      // 64^-0.5
}

// ---------------- K3: z[b,h,n] = x[b,n,:] . wz[b,h,:] ----------------
__global__ void z_kernel(const float* __restrict__ x, const float* __restrict__ wz,
                         float* __restrict__ z) {
  int blk = blockIdx.x;            // 4096 = b*2048 + n
  int b = blk >> 11;
  __shared__ float xr[kDim];
  int tid = threadIdx.x, wid = tid >> 6, lane = tid & 63;
  reinterpret_cast<float4*>(xr)[tid] = reinterpret_cast<const float4*>(x + (size_t)blk * kDim)[tid];
  __syncthreads();
#pragma unroll
  for (int hh = 0; hh < 4; ++hh) {
    int h = wid * 4 + hh;
    const float* wzr = wz + (size_t)(b * kHeads + h) * kDim;
    float s = 0.f;
    for (int k = lane; k < kDim; k += 64) s += xr[k] * wzr[k];
#pragma unroll
    for (int off = 32; off; off >>= 1) s += __shfl_xor(s, off);
    if (lane == 0) z[(size_t)(b * kHeads + h) * kN + (blk & 2047)] = s;
  }
}

// ---------------- bt-GEMM: C[m,n] = sum_k A[m,k]*B[n,k] ----------------
// BM=128, BN=64, BK=64 (512 blocks), 256 threads (4 waves, 2x2), wave tile 64x32.
// Double-buffered LDS + prefetch-before-compute, one barrier per K-step.
// MODE 0: write bf16 TRANSPOSED into vT[(b*1024+n)*2048 + (m&2047)]   (V-GEMM)
// MODE 1: write f32 + bias into y[m*1024+n]                            (projection)
template <int MODE>
__global__ __launch_bounds__(256, 2)
void gemm_bt_kernel(const u16* __restrict__ A, const u16* __restrict__ B,
                    void* __restrict__ Cout, const float* __restrict__ bias, int K) {
  __shared__ __align__(16) u16 As[2][128 * 64];
  __shared__ __align__(16) u16 Bs[2][64 * 64];
  int tid = threadIdx.x, lane = tid & 63, wid = tid >> 6;
  int wm = wid >> 1, wn = wid & 1;
  int lrow = lane & 15, kg = lane >> 4;
  int m0 = blockIdx.y * 128, n0 = blockIdx.x * 64;

  auto stage = [&](int buf, int k0) {
#pragma unroll
    for (int it = 0; it < 4; ++it) {
      int bchunk = it * 256 + wid * 64;
      int chunk = bchunk + lane;
      int row = chunk >> 3, cb = chunk & 7;
      int cs = cb ^ (row & 7);
      gload_lds16(A + (size_t)(m0 + row) * K + k0 + cs * 8, &As[buf][bchunk * 8]);
    }
#pragma unroll
    for (int it = 0; it < 2; ++it) {
      int bchunk = it * 256 + wid * 64;
      int chunk = bchunk + lane;
      int row = chunk >> 3, cb = chunk & 7;
      int cs = cb ^ (row & 7);
      gload_lds16(B + (size_t)(n0 + row) * K + k0 + cs * 8, &Bs[buf][bchunk * 8]);
    }
  };

  f32x4 acc[4][2];
#pragma unroll
  for (int i = 0; i < 4; ++i)
#pragma unroll
    for (int j = 0; j < 2; ++j) acc[i][j] = (f32x4){0.f, 0.f, 0.f, 0.f};

  stage(0, 0);
  __syncthreads();
  int buf = 0;
  for (int k0 = 0; k0 < K; k0 += 64) {
    if (k0 + 64 < K) stage(buf ^ 1, k0 + 64);
#pragma unroll
    for (int ks = 0; ks < 2; ++ks) {
      bf16x8 af[4], bfv[2];
#pragma unroll
      for (int mf = 0; mf < 4; ++mf) {
        int r = wm * 64 + mf * 16 + lrow;
        int c = (ks * 4 + kg) ^ (r & 7);
        af[mf] = *reinterpret_cast<const bf16x8*>(&As[buf][r * 64 + c * 8]);
      }
#pragma unroll
      for (int nf = 0; nf < 2; ++nf) {
        int r = wn * 32 + nf * 16 + lrow;
        int c = (ks * 4 + kg) ^ (r & 7);
        bfv[nf] = *reinterpret_cast<const bf16x8*>(&Bs[buf][r * 64 + c * 8]);
      }
#pragma unroll
      for (int mf = 0; mf < 4; ++mf)
#pragma unroll
        for (int nf = 0; nf < 2; ++nf)
          acc[mf][nf] = __builtin_amdgcn_mfma_f32_16x16x32_bf16(af[mf], bfv[nf], acc[mf][nf], 0, 0, 0);
    }
    __syncthreads();
    buf ^= 1;
  }

  if (MODE == 0) {
    u16* vT = (u16*)Cout;
#pragma unroll
    for (int mf = 0; mf < 4; ++mf) {
      int row0 = m0 + wm * 64 + mf * 16 + kg * 4;   // token index; 4 consecutive
      int bb = row0 >> 11, u = row0 & 2047;
#pragma unroll
      for (int nf = 0; nf < 2; ++nf) {
        int col = n0 + wn * 32 + nf * 16 + lrow;    // channel
        f32x4 a = acc[mf][nf];
        unsigned int lo = (unsigned int)f2bf(a.x) | ((unsigned int)f2bf(a.y) << 16);
        unsigned int hi = (unsigned int)f2bf(a.z) | ((unsigned int)f2bf(a.w) << 16);
        *reinterpret_cast<uint2*>(&vT[((size_t)(bb * kDim + col)) * kN + u]) = make_uint2(lo, hi);
      }
    }
  } else {
    float* y = (float*)Cout;
#pragma unroll
    for (int nf = 0; nf < 2; ++nf) {
      int col = n0 + wn * 32 + nf * 16 + lrow;
      float bv = bias[col];
#pragma unroll
      for (int mf = 0; mf < 4; ++mf) {
        int row0 = m0 + wm * 64 + mf * 16 + kg * 4;
        f32x4 a = acc[mf][nf];
        y[(size_t)(row0 + 0) * kDim + col] = a.x + bv;
        y[(size_t)(row0 + 1) * kDim + col] = a.y + bv;
        y[(size_t)(row0 + 2) * kDim + col] = a.z + bv;
        y[(size_t)(row0 + 3) * kDim + col] = a.w + bv;
      }
    }
  }
}

// ---------------- circular-conv GEMM with in-kernel softmax ----------------
// Per block (i0, bh): softmax of z row bh (redundant x16, cheap) written directly as
// 8 shifted LDS replicas, then outT[d,i] = sum_u vT[d,u]*attn[(u-i)&2047] via MFMA.
__global__ __launch_bounds__(256, 2)
void conv_kernel(const u16* __restrict__ vT, const float* __restrict__ z,
                 u16* __restrict__ oc) {
  static constexpr int RS = 2056;               // rep stride (u16); 2056*2 bytes = 16B multiple
  __shared__ __align__(16) u16 reps[8 * RS];
  __shared__ __align__(16) u16 vts[2][64 * 64];
  __shared__ float redm[4], reds[4];
  int tid = threadIdx.x, lane = tid & 63, wid = tid >> 6;
  int wm = wid >> 1, wn = wid & 1;
  int lrow = lane & 15, kg = lane >> 4;
  int i0 = blockIdx.x * 128;
  int bh = blockIdx.y;                          // b*16 + h
  int b = bh >> 4, h = bh & 15;

  // ---- softmax(z[bh,:]) -> 8 shifted replicas: reps[p][(j-p)&2047] = attn[j]
  {
    const float* zr = z + (size_t)bh * kN;
    float vv[8];
    float mx = -1e30f;
#pragma unroll
    for (int j = 0; j < 8; ++j) { vv[j] = zr[tid + j * 256]; mx = fmaxf(mx, vv[j]); }
#pragma unroll
    for (int off = 32; off; off >>= 1) mx = fmaxf(mx, __shfl_xor(mx, off));
    if (lane == 0) redm[wid] = mx;
    __syncthreads();
    mx = fmaxf(fmaxf(redm[0], redm[1]), fmaxf(redm[2], redm[3]));
    float s = 0.f;
#pragma unroll
    for (int j = 0; j < 8; ++j) { vv[j] = __expf(vv[j] - mx); s += vv[j]; }
#pragma unroll
    for (int off = 32; off; off >>= 1) s += __shfl_xor(s, off);
    if (lane == 0) reds[wid] = s;
    __syncthreads();
    s = reds[0] + reds[1] + reds[2] + reds[3];
    float inv = 1.0f / s;
#pragma unroll
    for (int j = 0; j < 8; ++j) {
      u16 a = f2bf(vv[j] * inv);
      int idx = tid + j * 256;
#pragma unroll
      for (int p = 0; p < 8; ++p) reps[p * RS + ((idx - p) & 2047)] = a;
    }
  }

  auto stage = [&](int buf, int u0) {
#pragma unroll
    for (int it = 0; it < 2; ++it) {
      int bchunk = it * 256 + wid * 64;
      int chunk = bchunk + lane;
      int d = chunk >> 3, cb = chunk & 7;
      int cs = cb ^ (d & 7);
      gload_lds16(vT + (size_t)(bh * 64 + d) * kN + u0 + cs * 8, &vts[buf][bchunk * 8]);
    }
  };

  f32x4 acc[2][4];
#pragma unroll
  for (int i = 0; i < 2; ++i)
#pragma unroll
    for (int j = 0; j < 4; ++j) acc[i][j] = (f32x4){0.f, 0.f, 0.f, 0.f};

  stage(0, 0);
  __syncthreads();                              // covers reps (lgkm) + vts buf0 (vmcnt)
  int buf = 0;
  for (int u0 = 0; u0 < kN; u0 += 64) {
    if (u0 + 64 < kN) stage(buf ^ 1, u0 + 64);
#pragma unroll
    for (int ks = 0; ks < 2; ++ks) {
      bf16x8 af[2], bfv[4];
#pragma unroll
      for (int mf = 0; mf < 2; ++mf) {
        int r = wm * 32 + mf * 16 + lrow;
        int c = (ks * 4 + kg) ^ (r & 7);
        af[mf] = *reinterpret_cast<const bf16x8*>(&vts[buf][r * 64 + c * 8]);
      }
#pragma unroll
      for (int nf = 0; nf < 4; ++nf) {
        int i = i0 + wn * 64 + nf * 16 + lrow;
        int s = (u0 + ks * 32 + kg * 8 - i) & 2047;
        int p = s & 7;
        bfv[nf] = *reinterpret_cast<const bf16x8*>(&reps[p * RS + (s & ~7)]);
      }
#pragma unroll
      for (int mf = 0; mf < 2; ++mf)
#pragma unroll
        for (int nf = 0; nf < 4; ++nf)
          acc[mf][nf] = __builtin_amdgcn_mfma_f32_16x16x32_bf16(af[mf], bfv[nf], acc[mf][nf], 0, 0, 0);
    }
    __syncthreads();
    buf ^= 1;
  }

  // store: oc[(b*2048 + i)*1024 + h*64 + d], 4 consecutive d per lane -> 8B store
#pragma unroll
  for (int mf = 0; mf < 2; ++mf) {
    int d = wm * 32 + mf * 16 + kg * 4;
#pragma unroll
    for (int nf = 0; nf < 4; ++nf) {
      int i = i0 + wn * 64 + nf * 16 + lrow;
      f32x4 a = acc[mf][nf];
      unsigned int lo = (unsigned int)f2bf(a.x) | ((unsigned int)f2bf(a.y) << 16);
      unsigned int hi = (unsigned int)f2bf(a.z) | ((unsigned int)f2bf(a.w) << 16);
      *reinterpret_cast<uint2*>(&oc[((size_t)(b * kN + i)) * kDim + h * 64 + d]) = make_uint2(lo, hi);
    }
  }
}

// ---------------- launch (6 dispatches) ----------------
extern "C" void kernel_launch(void* const* d_in, const int* in_sizes, int n_in,
                              void* d_out, int out_size, void* d_ws, size_t ws_size,
                              hipStream_t stream) {
  const float* x  = (const float*)d_in[0];
  const float* wq = (const float*)d_in[1];
  const float* wk = (const float*)d_in[2];
  const float* wv = (const float*)d_in[3];
  const float* wp = (const float*)d_in[4];
  const float* bp = (const float*)d_in[5];
  char* ws = (char*)d_ws;

  u16*   xb    = (u16*)(ws + OFF_XB);
  u16*   vTb   = (u16*)(ws + OFF_VT);
  u16*   ocb   = (u16*)(ws + OFF_OC);
  u16*   wvb   = (u16*)(ws + OFF_WVB);
  u16*   wpb   = (u16*)(ws + OFF_WPB);
  float* part  = (float*)(ws + OFF_PART);
  float* wz    = (float*)(ws + OFF_WZ);
  float* z     = (float*)(ws + OFF_Z);

  cvt_all_kernel<<<2176, 256, 0, stream>>>(x, wv, wp, xb, wvb, part);
  kwz_kernel<<<128, 256, 0, stream>>>(part, wk, wq, wz);
  z_kernel<<<4096, 256, 0, stream>>>(x, wz, z);
  // V-GEMM: v = x @ wv^T, written transposed per (b, channel) row
  gemm_bt_kernel<0><<<dim3(16, 32), 256, 0, stream>>>(xb, wvb, vTb, nullptr, kDim);
  // circular conv per (b,h) with fused softmax
  conv_kernel<<<dim3(16, 32), 256, 0, stream>>>(vTb, z, ocb);
  // projection: y = oc @ wp^T + bp (f32 out)
  gemm_bt_kernel<1><<<dim3(16, 32), 256, 0, stream>>>(ocb, wpb, (float*)d_out, bp, kDim);
}

// Round 9
// 204.127 us; speedup vs baseline: 1.1315x; 1.1315x over previous
//
#include <hip/hip_runtime.h>
#include <stdint.h>

typedef unsigned short u16;
typedef __bf16 bf16x8 __attribute__((ext_vector_type(8)));
typedef float f32x4 __attribute__((ext_vector_type(4)));

static constexpr int kDim   = 1024;
static constexpr int kHeads = 16;
static constexpr int kN     = 2048;   // sequence length (power of two!)
static constexpr int kB     = 2;
static constexpr int kTok   = 4096;   // kB * kN

// ---------------- workspace byte offsets ----------------
static constexpr size_t OFF_XB   = 0;                                   // x in bf16      [4096][1024]
static constexpr size_t OFF_VT   = OFF_XB   + (size_t)kTok*kDim*2;      // v^T bf16       [b*1024+c][2048]
static constexpr size_t OFF_OC   = OFF_VT   + (size_t)kTok*kDim*2;      // conv out bf16  [4096][1024]
static constexpr size_t OFF_WVB  = OFF_OC   + (size_t)kTok*kDim*2;      // wv bf16
static constexpr size_t OFF_WPB  = OFF_WVB  + (size_t)kDim*kDim*2;      // wp bf16 (contiguous after wvb!)
static constexpr size_t OFF_PART = OFF_WPB  + (size_t)kDim*kDim*2;      // [2][16][1024] f32 partial col-sums
static constexpr size_t OFF_XS   = OFF_PART + (size_t)kB*16*kDim*4;     // [2][1024] f32 xsum
static constexpr size_t OFF_KAVG = OFF_XS   + (size_t)kB*kDim*4;        // [2][16][64] f32
static constexpr size_t OFF_WZ   = OFF_KAVG + (size_t)kB*kHeads*64*4;   // [32][1024] f32
static constexpr size_t OFF_Z    = OFF_WZ   + (size_t)kB*kHeads*kDim*4; // [32][2048] f32

// ---------------- helpers ----------------
__device__ __forceinline__ u16 f2bf(float f) {
  unsigned int u = __builtin_bit_cast(unsigned int, f);
  u = (u + 0x7FFFu + ((u >> 16) & 1u)) >> 16;   // RNE
  return (u16)u;
}

// async global->LDS, 16B per lane; LDS dest is wave-uniform base + lane*16
__device__ __forceinline__ void gload_lds16(const void* g, void* l) {
  __builtin_amdgcn_global_load_lds(
      (const __attribute__((address_space(1))) unsigned int*)g,
      (__attribute__((address_space(3))) unsigned int*)l, 16, 0, 0);
}

// ---------------- K1: all conversions + x column partial sums ----------------
// blocks [0,2048): wv|wp f32 -> bf16 (contiguous out). blocks [2048,2176): x -> xb + part.
__global__ void cvt_all_kernel(const float* __restrict__ x, const float* __restrict__ wv,
                               const float* __restrict__ wp, u16* __restrict__ xb,
                               u16* __restrict__ wvb, float* __restrict__ part) {
  int bid = blockIdx.x;
  if (bid < 2048) {
    int i = bid * 256 + threadIdx.x;             // [0, 524288) float4s
    const int half = kDim * kDim / 4;            // 262144
    float4 f = (i < half) ? reinterpret_cast<const float4*>(wv)[i]
                          : reinterpret_cast<const float4*>(wp)[i - half];
    unsigned int lo = (unsigned int)f2bf(f.x) | ((unsigned int)f2bf(f.y) << 16);
    unsigned int hi = (unsigned int)f2bf(f.z) | ((unsigned int)f2bf(f.w) << 16);
    reinterpret_cast<uint2*>(wvb)[i] = make_uint2(lo, hi);
    return;
  }
  int b2 = bid - 2048;                           // 128 blocks: b(2) x nchunk(16) x cchunk(4)
  int cc = b2 & 3, nc = (b2 >> 2) & 15, b = b2 >> 6;
  int tid = threadIdx.x, rg = tid >> 6, cl = tid & 63;
  int col = cc * 256 + cl * 4;
  size_t base = (size_t)b * kN + nc * 128;
  float4 s = make_float4(0.f, 0.f, 0.f, 0.f);
  for (int n = rg; n < 128; n += 4) {
    size_t idx = (base + n) * kDim + col;
    float4 v = *reinterpret_cast<const float4*>(&x[idx]);
    unsigned int lo = (unsigned int)f2bf(v.x) | ((unsigned int)f2bf(v.y) << 16);
    unsigned int hi = (unsigned int)f2bf(v.z) | ((unsigned int)f2bf(v.w) << 16);
    *reinterpret_cast<uint2*>(&xb[idx]) = make_uint2(lo, hi);
    s.x += v.x; s.y += v.y; s.z += v.z; s.w += v.w;
  }
  __shared__ float ps[4][256];
  ps[rg][cl * 4 + 0] = s.x; ps[rg][cl * 4 + 1] = s.y;
  ps[rg][cl * 4 + 2] = s.z; ps[rg][cl * 4 + 3] = s.w;
  __syncthreads();
  float tot = ps[0][tid] + ps[1][tid] + ps[2][tid] + ps[3][tid];
  part[((size_t)(b * 16 + nc)) * kDim + cc * 256 + tid] = tot;
}

// ---------------- K2: xsum[b][c] = sum over 16 chunks of part (8 blocks x 256) ----
__global__ void xsumred_kernel(const float* __restrict__ part, float* __restrict__ xsum) {
  int i = blockIdx.x * 256 + threadIdx.x;        // [0, 2048) = b*1024 + c
  int b = i >> 10, c = i & 1023;
  float s = 0.f;
#pragma unroll
  for (int ch = 0; ch < 16; ++ch) s += part[((size_t)(b * 16 + ch)) * kDim + c];
  xsum[i] = s;
}

// ---------------- K3: kavg[b,h,d] = (1/N) xsum[b,:].wk[h*64+d,:] (2048 x 64) ------
__global__ void kavg_kernel(const float* __restrict__ xsum, const float* __restrict__ wk,
                            float* __restrict__ kavg) {
  int o = blockIdx.x;              // [0,2048) = b*1024 + h*64 + d
  int b = o >> 10;
  int lane = threadIdx.x;          // 64 threads
  const float* wkr = wk + (size_t)(o & 1023) * kDim;
  const float* xs = xsum + b * kDim;
  float s = 0.f;
  for (int k = lane; k < kDim; k += 64) s += xs[k] * wkr[k];
#pragma unroll
  for (int off = 32; off; off >>= 1) s += __shfl_xor(s, off);
  if (lane == 0) kavg[o] = s * (1.0f / (float)kN);
}

// ---------------- K4: wz[bh,col] = scale * kavg[bh,:].wq[h*64+:,col] (32x8, 128) ---
__global__ void wz_kernel(const float* __restrict__ kavg, const float* __restrict__ wq,
                          float* __restrict__ wz) {
  int bh = blockIdx.x, h = bh & 15;
  int col = blockIdx.y * 128 + threadIdx.x;
  __shared__ float kl[64];
  if (threadIdx.x < 64) kl[threadIdx.x] = kavg[bh * 64 + threadIdx.x];
  __syncthreads();
  float a = 0.f;
  const float* wqc = wq + (size_t)h * 64 * kDim + col;
#pragma unroll
  for (int dd = 0; dd < 64; ++dd) a += kl[dd] * wqc[(size_t)dd * kDim];
  wz[(size_t)bh * kDim + col] = a * 0.125f;      // 64^-0.5
}

// ---------------- K5: z[b,h,n] = x[b,n,:] . wz[b,h,:] ----------------
__global__ void z_kernel(const float* __restrict__ x, const float* __restrict__ wz,
                         float* __restrict__ z) {
  int blk = blockIdx.x;            // 4096 = b*2048 + n
  int b = blk >> 11;
  __shared__ float xr[kDim];
  int tid = threadIdx.x, wid = tid >> 6, lane = tid & 63;
  reinterpret_cast<float4*>(xr)[tid] = reinterpret_cast<const float4*>(x + (size_t)blk * kDim)[tid];
  __syncthreads();
#pragma unroll
  for (int hh = 0; hh < 4; ++hh) {
    int h = wid * 4 + hh;
    const float* wzr = wz + (size_t)(b * kHeads + h) * kDim;
    float s = 0.f;
    for (int k = lane; k < kDim; k += 64) s += xr[k] * wzr[k];
#pragma unroll
    for (int off = 32; off; off >>= 1) s += __shfl_xor(s, off);
    if (lane == 0) z[(size_t)(b * kHeads + h) * kN + (blk & 2047)] = s;
  }
}

// ---------------- bt-GEMM: C[m,n] = sum_k A[m,k]*B[n,k] ----------------
// BM=128, BN=64, BK=64 (512 blocks), 256 threads (4 waves, 2x2), wave tile 64x32.
// Double-buffered LDS + prefetch-before-compute, one barrier per K-step.
// MODE 0: write bf16 TRANSPOSED into vT[(b*1024+n)*2048 + (m&2047)]   (V-GEMM)
// MODE 1: write f32 + bias into y[m*1024+n]                            (projection)
template <int MODE>
__global__ __launch_bounds__(256, 2)
void gemm_bt_kernel(const u16* __restrict__ A, const u16* __restrict__ B,
                    void* __restrict__ Cout, const float* __restrict__ bias, int K) {
  __shared__ __align__(16) u16 As[2][128 * 64];
  __shared__ __align__(16) u16 Bs[2][64 * 64];
  int tid = threadIdx.x, lane = tid & 63, wid = tid >> 6;
  int wm = wid >> 1, wn = wid & 1;
  int lrow = lane & 15, kg = lane >> 4;
  int m0 = blockIdx.y * 128, n0 = blockIdx.x * 64;

  auto stage = [&](int buf, int k0) {
#pragma unroll
    for (int it = 0; it < 4; ++it) {
      int bchunk = it * 256 + wid * 64;
      int chunk = bchunk + lane;
      int row = chunk >> 3, cb = chunk & 7;
      int cs = cb ^ (row & 7);
      gload_lds16(A + (size_t)(m0 + row) * K + k0 + cs * 8, &As[buf][bchunk * 8]);
    }
#pragma unroll
    for (int it = 0; it < 2; ++it) {
      int bchunk = it * 256 + wid * 64;
      int chunk = bchunk + lane;
      int row = chunk >> 3, cb = chunk & 7;
      int cs = cb ^ (row & 7);
      gload_lds16(B + (size_t)(n0 + row) * K + k0 + cs * 8, &Bs[buf][bchunk * 8]);
    }
  };

  f32x4 acc[4][2];
#pragma unroll
  for (int i = 0; i < 4; ++i)
#pragma unroll
    for (int j = 0; j < 2; ++j) acc[i][j] = (f32x4){0.f, 0.f, 0.f, 0.f};

  stage(0, 0);
  __syncthreads();
  int buf = 0;
  for (int k0 = 0; k0 < K; k0 += 64) {
    if (k0 + 64 < K) stage(buf ^ 1, k0 + 64);
#pragma unroll
    for (int ks = 0; ks < 2; ++ks) {
      bf16x8 af[4], bfv[2];
#pragma unroll
      for (int mf = 0; mf < 4; ++mf) {
        int r = wm * 64 + mf * 16 + lrow;
        int c = (ks * 4 + kg) ^ (r & 7);
        af[mf] = *reinterpret_cast<const bf16x8*>(&As[buf][r * 64 + c * 8]);
      }
#pragma unroll
      for (int nf = 0; nf < 2; ++nf) {
        int r = wn * 32 + nf * 16 + lrow;
        int c = (ks * 4 + kg) ^ (r & 7);
        bfv[nf] = *reinterpret_cast<const bf16x8*>(&Bs[buf][r * 64 + c * 8]);
      }
#pragma unroll
      for (int mf = 0; mf < 4; ++mf)
#pragma unroll
        for (int nf = 0; nf < 2; ++nf)
          acc[mf][nf] = __builtin_amdgcn_mfma_f32_16x16x32_bf16(af[mf], bfv[nf], acc[mf][nf], 0, 0, 0);
    }
    __syncthreads();
    buf ^= 1;
  }

  if (MODE == 0) {
    u16* vT = (u16*)Cout;
#pragma unroll
    for (int mf = 0; mf < 4; ++mf) {
      int row0 = m0 + wm * 64 + mf * 16 + kg * 4;   // token index; 4 consecutive
      int bb = row0 >> 11, u = row0 & 2047;
#pragma unroll
      for (int nf = 0; nf < 2; ++nf) {
        int col = n0 + wn * 32 + nf * 16 + lrow;    // channel
        f32x4 a = acc[mf][nf];
        unsigned int lo = (unsigned int)f2bf(a.x) | ((unsigned int)f2bf(a.y) << 16);
        unsigned int hi = (unsigned int)f2bf(a.z) | ((unsigned int)f2bf(a.w) << 16);
        *reinterpret_cast<uint2*>(&vT[((size_t)(bb * kDim + col)) * kN + u]) = make_uint2(lo, hi);
      }
    }
  } else {
    float* y = (float*)Cout;
#pragma unroll
    for (int nf = 0; nf < 2; ++nf) {
      int col = n0 + wn * 32 + nf * 16 + lrow;
      float bv = bias[col];
#pragma unroll
      for (int mf = 0; mf < 4; ++mf) {
        int row0 = m0 + wm * 64 + mf * 16 + kg * 4;
        f32x4 a = acc[mf][nf];
        y[(size_t)(row0 + 0) * kDim + col] = a.x + bv;
        y[(size_t)(row0 + 1) * kDim + col] = a.y + bv;
        y[(size_t)(row0 + 2) * kDim + col] = a.z + bv;
        y[(size_t)(row0 + 3) * kDim + col] = a.w + bv;
      }
    }
  }
}

// ---------------- circular-conv GEMM with in-kernel softmax ----------------
// Per block (bh, i0): softmax of z row bh (redundant x16, cheap) written directly as
// 8 shifted LDS replicas, then outT[d,i] = sum_u vT[d,u]*attn[(u-i)&2047] via MFMA.
// grid = (bh=32, i=16) bh-MAJOR: linear id = bh + 32*i  ->  id%8 = bh%8, so all 16
// i-tiles of one bh land on ONE XCD -> its 256KB vT slice stays L2-resident (T1).
__global__ __launch_bounds__(256, 2)
void conv_kernel(const u16* __restrict__ vT, const float* __restrict__ z,
                 u16* __restrict__ oc) {
  static constexpr int RS = 2056;               // rep stride (u16); 2056*2 bytes = 16B multiple
  __shared__ __align__(16) u16 reps[8 * RS];
  __shared__ __align__(16) u16 vts[2][64 * 64];
  __shared__ float redm[4], reds[4];
  int tid = threadIdx.x, lane = tid & 63, wid = tid >> 6;
  int wm = wid >> 1, wn = wid & 1;
  int lrow = lane & 15, kg = lane >> 4;
  int bh = blockIdx.x;                          // b*16 + h   (bh-major!)
  int i0 = blockIdx.y * 128;
  int b = bh >> 4, h = bh & 15;

  // ---- softmax(z[bh,:]) -> 8 shifted replicas: reps[p][(j-p)&2047] = attn[j]
  {
    const float* zr = z + (size_t)bh * kN;
    float vv[8];
    float mx = -1e30f;
#pragma unroll
    for (int j = 0; j < 8; ++j) { vv[j] = zr[tid + j * 256]; mx = fmaxf(mx, vv[j]); }
#pragma unroll
    for (int off = 32; off; off >>= 1) mx = fmaxf(mx, __shfl_xor(mx, off));
    if (lane == 0) redm[wid] = mx;
    __syncthreads();
    mx = fmaxf(fmaxf(redm[0], redm[1]), fmaxf(redm[2], redm[3]));
    float s = 0.f;
#pragma unroll
    for (int j = 0; j < 8; ++j) { vv[j] = __expf(vv[j] - mx); s += vv[j]; }
#pragma unroll
    for (int off = 32; off; off >>= 1) s += __shfl_xor(s, off);
    if (lane == 0) reds[wid] = s;
    __syncthreads();
    s = reds[0] + reds[1] + reds[2] + reds[3];
    float inv = 1.0f / s;
#pragma unroll
    for (int j = 0; j < 8; ++j) {
      u16 a = f2bf(vv[j] * inv);
      int idx = tid + j * 256;
#pragma unroll
      for (int p = 0; p < 8; ++p) reps[p * RS + ((idx - p) & 2047)] = a;
    }
  }

  auto stage = [&](int buf, int u0) {
#pragma unroll
    for (int it = 0; it < 2; ++it) {
      int bchunk = it * 256 + wid * 64;
      int chunk = bchunk + lane;
      int d = chunk >> 3, cb = chunk & 7;
      int cs = cb ^ (d & 7);
      gload_lds16(vT + (size_t)(bh * 64 + d) * kN + u0 + cs * 8, &vts[buf][bchunk * 8]);
    }
  };

  f32x4 acc[2][4];
#pragma unroll
  for (int i = 0; i < 2; ++i)
#pragma unroll
    for (int j = 0; j < 4; ++j) acc[i][j] = (f32x4){0.f, 0.f, 0.f, 0.f};

  stage(0, 0);
  __syncthreads();                              // covers reps (lgkm) + vts buf0 (vmcnt)
  int buf = 0;
  for (int u0 = 0; u0 < kN; u0 += 64) {
    if (u0 + 64 < kN) stage(buf ^ 1, u0 + 64);
#pragma unroll
    for (int ks = 0; ks < 2; ++ks) {
      bf16x8 af[2], bfv[4];
#pragma unroll
      for (int mf = 0; mf < 2; ++mf) {
        int r = wm * 32 + mf * 16 + lrow;
        int c = (ks * 4 + kg) ^ (r & 7);
        af[mf] = *reinterpret_cast<const bf16x8*>(&vts[buf][r * 64 + c * 8]);
      }
#pragma unroll
      for (int nf = 0; nf < 4; ++nf) {
        int i = i0 + wn * 64 + nf * 16 + lrow;
        int s = (u0 + ks * 32 + kg * 8 - i) & 2047;
        int p = s & 7;
        bfv[nf] = *reinterpret_cast<const bf16x8*>(&reps[p * RS + (s & ~7)]);
      }
#pragma unroll
      for (int mf = 0; mf < 2; ++mf)
#pragma unroll
        for (int nf = 0; nf < 4; ++nf)
          acc[mf][nf] = __builtin_amdgcn_mfma_f32_16x16x32_bf16(af[mf], bfv[nf], acc[mf][nf], 0, 0, 0);
    }
    __syncthreads();
    buf ^= 1;
  }

  // store: oc[(b*2048 + i)*1024 + h*64 + d], 4 consecutive d per lane -> 8B store
#pragma unroll
  for (int mf = 0; mf < 2; ++mf) {
    int d = wm * 32 + mf * 16 + kg * 4;
#pragma unroll
    for (int nf = 0; nf < 4; ++nf) {
      int i = i0 + wn * 64 + nf * 16 + lrow;
      f32x4 a = acc[mf][nf];
      unsigned int lo = (unsigned int)f2bf(a.x) | ((unsigned int)f2bf(a.y) << 16);
      unsigned int hi = (unsigned int)f2bf(a.z) | ((unsigned int)f2bf(a.w) << 16);
      *reinterpret_cast<uint2*>(&oc[((size_t)(b * kN + i)) * kDim + h * 64 + d]) = make_uint2(lo, hi);
    }
  }
}

// ---------------- launch (8 dispatches) ----------------
extern "C" void kernel_launch(void* const* d_in, const int* in_sizes, int n_in,
                              void* d_out, int out_size, void* d_ws, size_t ws_size,
                              hipStream_t stream) {
  const float* x  = (const float*)d_in[0];
  const float* wq = (const float*)d_in[1];
  const float* wk = (const float*)d_in[2];
  const float* wv = (const float*)d_in[3];
  const float* wp = (const float*)d_in[4];
  const float* bp = (const float*)d_in[5];
  char* ws = (char*)d_ws;

  u16*   xb    = (u16*)(ws + OFF_XB);
  u16*   vTb   = (u16*)(ws + OFF_VT);
  u16*   ocb   = (u16*)(ws + OFF_OC);
  u16*   wvb   = (u16*)(ws + OFF_WVB);
  u16*   wpb   = (u16*)(ws + OFF_WPB);
  float* part  = (float*)(ws + OFF_PART);
  float* xsum  = (float*)(ws + OFF_XS);
  float* kavg  = (float*)(ws + OFF_KAVG);
  float* wz    = (float*)(ws + OFF_WZ);
  float* z     = (float*)(ws + OFF_Z);

  cvt_all_kernel<<<2176, 256, 0, stream>>>(x, wv, wp, xb, wvb, part);
  xsumred_kernel<<<8, 256, 0, stream>>>(part, xsum);
  kavg_kernel<<<2048, 64, 0, stream>>>(xsum, wk, kavg);
  wz_kernel<<<dim3(32, 8), 128, 0, stream>>>(kavg, wq, wz);
  z_kernel<<<4096, 256, 0, stream>>>(x, wz, z);
  // V-GEMM: v = x @ wv^T, written transposed per (b, channel) row
  gemm_bt_kernel<0><<<dim3(16, 32), 256, 0, stream>>>(xb, wvb, vTb, nullptr, kDim);
  // circular conv per (b,h) with fused softmax; bh-major grid for XCD L2 locality
  conv_kernel<<<dim3(32, 16), 256, 0, stream>>>(vTb, z, ocb);
  // projection: y = oc @ wp^T + bp (f32 out)
  gemm_bt_kernel<1><<<dim3(16, 32), 256, 0, stream>>>(ocb, wpb, (float*)d_out, bp, kDim);
}